// Round 6
// baseline (1602.085 us; speedup 1.0000x reference)
//
#include <hip/hip_runtime.h>
#include <cstdint>
#include <cstddef>

// ---------------------------------------------------------------------------
// SpaceFormerImputation on MI355X (gfx950) — round 6.
// vs round 5 (1547 us): score at 30% occupancy (pinned 3 waves/SIMD, LDS fits
// 4); PV at 4 blocks/CU; FF2 at 1 block/CU. Changes:
//  * score_fused __launch_bounds__(256,4) -> 4 blocks/CU.
//  * gemm_bt gains grid.z split-K (kShift = z*K, C += z*slabStride). Used for
//    PV (8 chunks K=1024, 2048 blocks), FF2 (2 chunks), head (2 chunks).
//    Slabs are bf16 (8x8MB, same 64MB as old f32 Oacc).
//  * Slab reduction fused into pv_ln (8 slabs), ff_ln (2 slabs + bias +
//    residual + LN), gather_out_k (2 slabs + bias at gathered cols).
// Runtime dtype flags: [0] mask fmt 0=i32,1=u8,2=bf16,3=f32; [1] idx int64;
// [2] float world f32(1)/bf16(0).
// ---------------------------------------------------------------------------

typedef unsigned short u16;
typedef __bf16 bf16x8 __attribute__((ext_vector_type(8)));
typedef float f32x4 __attribute__((ext_vector_type(4)));

#define GAMMA_C 0.5f
#define SCALE_C 0.04419417382415922f   // 1/sqrt(512)
#define NG      (8192 * 102)
#define SLAB    ((size_t)8192 * 512)

__device__ __forceinline__ float b2f(u16 u) {
  union { unsigned int i; float f; } c; c.i = ((unsigned int)u) << 16; return c.f;
}
__device__ __forceinline__ u16 f2b(float f) {
  union { float f; unsigned int i; } c; c.f = f;
  unsigned int u = c.i + 0x7FFFu + ((c.i >> 16) & 1u);
  return (u16)(u >> 16);
}
__device__ __forceinline__ float gelu_exact(float x) {
  return 0.5f * x * (1.0f + erff(x * 0.70710678118654752f));
}
__device__ __forceinline__ int idx_at(const void* p, int i, int i64) {
  return i64 ? (int)((const long long*)p)[i] : ((const int*)p)[i];
}
__device__ __forceinline__ float fl_at(const void* p, size_t i, int f32m) {
  return f32m ? ((const float*)p)[i] : b2f(((const u16*)p)[i]);
}
__device__ __forceinline__ void mask8(const void* m, size_t base, int f, bool o[8]) {
  if (f == 1) {
    unsigned long long v = *(const unsigned long long*)((const unsigned char*)m + base);
#pragma unroll
    for (int e = 0; e < 8; ++e) o[e] = ((v >> (8 * e)) & 0xFF) != 0;
  } else if (f == 0) {
    const uint4 a = *(const uint4*)((const int*)m + base);
    const uint4 b = *(const uint4*)((const int*)m + base + 4);
    o[0] = a.x; o[1] = a.y; o[2] = a.z; o[3] = a.w;
    o[4] = b.x; o[5] = b.y; o[6] = b.z; o[7] = b.w;
  } else if (f == 2) {
    const uint4 v = *(const uint4*)((const u16*)m + base);
    const u16* p = (const u16*)&v;
#pragma unroll
    for (int e = 0; e < 8; ++e) o[e] = p[e] != 0;
  } else {
    const uint4 a = *(const uint4*)((const float*)m + base);
    const uint4 b = *(const uint4*)((const float*)m + base + 4);
    o[0] = a.x; o[1] = a.y; o[2] = a.z; o[3] = a.w;
    o[4] = b.x; o[5] = b.y; o[6] = b.z; o[7] = b.w;
  }
}

#define GLD16(g, l) __builtin_amdgcn_global_load_lds(                         \
    (const __attribute__((address_space(1))) void*)(g),                       \
    (__attribute__((address_space(3))) void*)(l), 16, 0, 0)

// ----------------------------- dtype sniffing ------------------------------
__global__ void detect_all(const unsigned char* __restrict__ rmask,
                           const void* __restrict__ xin,
                           const void* __restrict__ idx,
                           int* __restrict__ flags) {
  __shared__ int nz[4];
  __shared__ int mx, bl;
  const int t = threadIdx.x;
  if (t < 4) nz[t] = 0;
  if (t == 0) { mx = 0; bl = 0; }
  __syncthreads();
  int cnt = 0, lm = 0;
  for (int i = t; i < 4096; i += 256) {
    const int v = rmask[i];
    if (v) { ++cnt; if (v > lm) lm = v; }
  }
  if (cnt) atomicAdd(&nz[t & 3], cnt);
  if (lm) atomicMax(&mx, lm);
  int bcnt = 0;
  for (int i = t; i < 2048; i += 256) {
    const u16 u = ((const u16*)xin)[2 * i];
    const int e = (u >> 7) & 0xFF;
    if ((e >= 110 && e <= 141) || u == 0) ++bcnt;
  }
  atomicAdd(&bl, bcnt);
  __syncthreads();
  if (t == 0) {
    int f;
    if (nz[1] == 0 && nz[2] == 0 && nz[3] == 0) f = 0;
    else if (nz[0] == 0 && nz[1] == 0) f = 3;
    else if (mx <= 1) f = 1;
    else f = 2;
    flags[0] = f;
    flags[2] = (bl >= 1536) ? 0 : 1;
    int ok = 1, prev = -1;
    for (int j = 0; j < 102; ++j) {
      const int v = ((const int*)idx)[j];
      if (v <= prev || v < 0 || v >= 512) { ok = 0; break; }
      prev = v;
    }
    flags[1] = ok ? 0 : 1;
  }
}

// ----------------------- bitmask pack (1 bit/element) ----------------------
__global__ void bitmask_prep(const void* __restrict__ mr, const void* __restrict__ mf,
                             unsigned char* __restrict__ bmr, unsigned char* __restrict__ bmf,
                             const int* __restrict__ flags) {
  const int i = blockIdx.x * 256 + threadIdx.x;   // byte index, 8192*1024 total
  const int f = flags[0];
  bool mk[8];
  mask8(mr, (size_t)i * 8, f, mk);
  unsigned char b = 0;
#pragma unroll
  for (int e = 0; e < 8; ++e) b |= (unsigned char)mk[e] << e;
  bmr[i] = b;
  mask8(mf, (size_t)i * 8, f, mk);
  b = 0;
#pragma unroll
  for (int e = 0; e < 8; ++e) b |= (unsigned char)mk[e] << e;
  bmf[i] = b;
}

// ---------------------- transpose + convert to bf16 ------------------------
struct PtrPack { const void* p[11]; };
__global__ void transpose_cvt_b(PtrPack srcs, u16* __restrict__ out,
                                const int* __restrict__ flags) {
  __shared__ u16 tile[32][33];
  const void* in = srcs.p[blockIdx.z];
  u16* o = out + (size_t)blockIdx.z * 512 * 512;
  const int f32m = flags[2];
  const int c0 = blockIdx.x * 32, r0 = blockIdx.y * 32;
  const int tx = threadIdx.x, ty = threadIdx.y;   // (32,8)
  for (int i = ty; i < 32; i += 8) {
    const size_t src = (size_t)(r0 + i) * 512 + (c0 + tx);
    tile[i][tx] = f32m ? f2b(((const float*)in)[src]) : ((const u16*)in)[src];
  }
  __syncthreads();
  for (int i = ty; i < 32; i += 8)
    o[(size_t)(c0 + i) * 512 + (r0 + tx)] = tile[tx][i];
}
__global__ void transpose_cvt(const void* __restrict__ in, u16* __restrict__ out,
                              int R, int C, const int* __restrict__ flags) {
  __shared__ u16 tile[32][33];
  const int f32m = flags[2];
  const int c0 = blockIdx.x * 32, r0 = blockIdx.y * 32;
  const int tx = threadIdx.x, ty = threadIdx.y;
  for (int i = ty; i < 32; i += 8) {
    const size_t src = (size_t)(r0 + i) * C + (c0 + tx);
    tile[i][tx] = f32m ? f2b(((const float*)in)[src]) : ((const u16*)in)[src];
  }
  __syncthreads();
  for (int i = ty; i < 32; i += 8)
    out[(size_t)(c0 + i) * R + (r0 + tx)] = tile[tx][i];
}

// ------------------------------ small utils --------------------------------
__global__ void cvt_to_bf16(const void* __restrict__ in, u16* __restrict__ out,
                            int n, const int* __restrict__ flags) {
  const int i = blockIdx.x * blockDim.x + threadIdx.x;
  if (i < n)
    out[i] = flags[2] ? f2b(((const float*)in)[i]) : ((const u16*)in)[i];
}
__global__ void zero_f32(float* __restrict__ p, int n) {
  const int i = blockIdx.x * blockDim.x + threadIdx.x;
  if (i < n) p[i] = 0.f;
}
__global__ void zero_drop(u16* __restrict__ dx, const void* __restrict__ idx,
                          const int* __restrict__ flags) {
  const int i = blockIdx.x * blockDim.x + threadIdx.x;
  if (i < NG) {
    const int row = i / 102;
    dx[(size_t)row * 512 + idx_at(idx, i, flags[1])] = 0;
  }
}
// out0 = x gathered; out1 = (headslab0+headslab1+head_b) gathered
__global__ void gather_out_k(const void* __restrict__ x, const u16* __restrict__ hs,
                             const void* __restrict__ hb,
                             const void* __restrict__ idx, void* __restrict__ out,
                             const int* __restrict__ flags) {
  const int i = blockIdx.x * blockDim.x + threadIdx.x;
  if (i < NG) {
    const int row = i / 102;
    const int c = idx_at(idx, i, flags[1]);
    const size_t src = (size_t)row * 512 + c;
    const float hv = b2f(hs[src]) + b2f(hs[src + SLAB]) + fl_at(hb, c, flags[2]);
    if (flags[2]) {
      ((float*)out)[i] = ((const float*)x)[src];
      ((float*)out)[NG + i] = hv;
    } else {
      ((u16*)out)[i] = ((const u16*)x)[src];
      ((u16*)out)[NG + i] = f2b(hv);
    }
  }
}

// ------------------------------ GEMM (B^T) ---------------------------------
// C[M,Nn] = A[M,K] @ Bt[Nn,K]^T (bf16). 128x128 tile, BK=64, 2x2 waves,
// 16x16x32 MFMA, XOR-swizzled LDS. grid.z = split-K chunk: reads A/Bt at
// k-offset z*K, writes C + z*slabStride. modes: 0 plain(+bias), 1 gelu(+bias),
// 2 QKV split (n0<2048 -> C; n0>=2048 -> transposed into aux=Vt).
__global__ __launch_bounds__(256, 4)
void gemm_bt(const u16* __restrict__ A, int lda,
             const u16* __restrict__ Bt, int ldb,
             u16* __restrict__ C, int ldc,
             int K, int mode, const void* __restrict__ bias,
             const int* __restrict__ flags, u16* __restrict__ aux,
             long long slabStride) {
  __shared__ alignas(16) u16 smem[16384];
  u16* As = smem;
  u16* Bs = smem + 8192;
  const int tid = threadIdx.x;
  const int lane = tid & 63, wave = tid >> 6;
  const int l15 = lane & 15, l4 = lane >> 4;
  const int wm = (wave >> 1) << 6, wn = (wave & 1) << 6;
  const int m0 = blockIdx.y << 7, n0 = blockIdx.x << 7;
  const size_t kShift = (size_t)blockIdx.z * (size_t)K;
  C += (size_t)blockIdx.z * (size_t)slabStride;

  f32x4 acc[4][4];
#pragma unroll
  for (int i = 0; i < 4; ++i)
#pragma unroll
    for (int j = 0; j < 4; ++j) acc[i][j] = (f32x4){0.f, 0.f, 0.f, 0.f};

  const int lrow = lane >> 3;
  const int lcg = (lane & 7) ^ lrow;
  const u16* aG = A + kShift + (size_t)(m0 + wave * 8 + lrow) * lda + lcg * 8;
  const u16* bG = Bt + kShift + (size_t)(n0 + wave * 8 + lrow) * ldb + lcg * 8;
  u16* asDst = &As[(wave * 8) * 64];
  u16* bsDst = &Bs[(wave * 8) * 64];
  const int swz = (l15 & 7) << 3;

  for (int k0 = 0; k0 < K; k0 += 64) {
#pragma unroll
    for (int r = 0; r < 4; ++r) {
      GLD16(aG + (size_t)(r * 32) * lda + k0, asDst + r * 32 * 64);
      GLD16(bG + (size_t)(r * 32) * ldb + k0, bsDst + r * 32 * 64);
    }
    __syncthreads();
#pragma unroll
    for (int kk = 0; kk < 2; ++kk) {
      bf16x8 a[4], b[4];
      const int koff = (((kk << 2) + l4) << 3) ^ swz;
#pragma unroll
      for (int i = 0; i < 4; ++i) {
        a[i] = *(const bf16x8*)&As[(wm + (i << 4) + l15) * 64 + koff];
        b[i] = *(const bf16x8*)&Bs[(wn + (i << 4) + l15) * 64 + koff];
      }
#pragma unroll
      for (int i = 0; i < 4; ++i)
#pragma unroll
        for (int j = 0; j < 4; ++j)
          acc[i][j] = __builtin_amdgcn_mfma_f32_16x16x32_bf16(a[i], b[j], acc[i][j], 0, 0, 0);
    }
    __syncthreads();
  }

  const int f32m = flags[2];

  if (mode == 2 && n0 >= 2048) {        // V part -> transposed store into Vt
#pragma unroll
    for (int i = 0; i < 4; ++i) {
      const int rbase = m0 + wm + (i << 4) + l4 * 4;
#pragma unroll
      for (int j = 0; j < 4; ++j) {
        const int gn = n0 - 2048 + wn + (j << 4) + l15;
        ushort4 pk;
        pk.x = f2b(acc[i][j][0]); pk.y = f2b(acc[i][j][1]);
        pk.z = f2b(acc[i][j][2]); pk.w = f2b(acc[i][j][3]);
        *(ushort4*)&aux[(size_t)gn * 8192 + rbase] = pk;
      }
    }
    return;
  }

  // phase 1: transform in C-frag layout, bf16 into swizzled LDS
#pragma unroll
  for (int i = 0; i < 4; ++i) {
    const int rl0 = wm + (i << 4) + l4 * 4;
#pragma unroll
    for (int j = 0; j < 4; ++j) {
      const int cl = wn + (j << 4) + l15;
      float bv = 0.f;
      if (bias) bv = fl_at(bias, n0 + cl, f32m);
      const int chunk = cl >> 3, within = cl & 7;
#pragma unroll
      for (int r = 0; r < 4; ++r) {
        const int rl = rl0 + r;
        float v = acc[i][j][r] + bv;
        if (mode == 1) v = gelu_exact(v);
        const int wchunk = (chunk & 8) | ((chunk ^ rl) & 7);
        smem[rl * 128 + wchunk * 8 + within] = f2b(v);
      }
    }
  }
  __syncthreads();

  // phase 2: vectorized stores
  const int r = tid >> 1, h = tid & 1;
  const int grow = m0 + r;
#pragma unroll
  for (int cb = 0; cb < 8; ++cb) {
    const int chunkidx = h * 8 + cb;
    const int rchunk = (chunkidx & 8) | ((chunkidx ^ r) & 7);
    uint4 raw = *(const uint4*)&smem[r * 128 + rchunk * 8];
    *(uint4*)&C[(size_t)grow * ldc + n0 + chunkidx * 8] = raw;
  }
}

// --------------------------- fused dual score v2 ---------------------------
// W[m,n] = maskr?0:exp(sr*scale) + gamma*(maskf?0:exp(sf*scale)); row sums via
// shfl reduce + atomics. sr parked in packed-bf16 VGPRs between the two
// K-loops; mask bit-tiles in LDS; 36KB LDS, 4 blocks/CU.
__global__ __launch_bounds__(256, 4)
void score_fused(const u16* __restrict__ P,          // [8192][2048] Qr|Kr|Qf|Kf
                 const unsigned char* __restrict__ bmr,
                 const unsigned char* __restrict__ bmf,
                 u16* __restrict__ W, float* __restrict__ lvec) {
  __shared__ alignas(16) u16 stage[16384];            // 32 KB staging / w-tile
  __shared__ unsigned long long mrs[256], mfs[256];   // 4 KB mask bit-tiles
  const int tid = threadIdx.x;
  const int lane = tid & 63, wave = tid >> 6;
  const int l15 = lane & 15, l4 = lane >> 4;
  const int wm = (wave >> 1) << 6, wn = (wave & 1) << 6;
  const int m0 = blockIdx.y << 7, n0 = blockIdx.x << 7;

  {  // mask tiles -> LDS (ordering vs phase 2 covered by K-loop barriers)
    const int r = tid >> 1, hh = tid & 1;
    const size_t mo = (size_t)(m0 + r) * 1024 + (n0 >> 3) + hh * 8;
    mrs[tid] = *(const unsigned long long*)&bmr[mo];
    mfs[tid] = *(const unsigned long long*)&bmf[mo];
  }

  const int lrow = lane >> 3;
  const int lcg = (lane & 7) ^ lrow;
  const int swz = (l15 & 7) << 3;
  u16* asDst = &stage[(wave * 8) * 64];
  u16* bsDst = &stage[8192 + (wave * 8) * 64];

  unsigned int srp[4][4][2];   // packed bf16 sr*scale
  f32x4 acc[4][4];

  for (int p = 0; p < 2; ++p) {
#pragma unroll
    for (int i = 0; i < 4; ++i)
#pragma unroll
      for (int j = 0; j < 4; ++j) acc[i][j] = (f32x4){0.f, 0.f, 0.f, 0.f};

    const u16* aG = P + (p ? 1024 : 0) + (size_t)(m0 + wave * 8 + lrow) * 2048 + lcg * 8;
    const u16* bG = P + (p ? 1536 : 512) + (size_t)(n0 + wave * 8 + lrow) * 2048 + lcg * 8;

    for (int k0 = 0; k0 < 512; k0 += 64) {
#pragma unroll
      for (int r = 0; r < 4; ++r) {
        GLD16(aG + (size_t)(r * 32) * 2048 + k0, asDst + r * 32 * 64);
        GLD16(bG + (size_t)(r * 32) * 2048 + k0, bsDst + r * 32 * 64);
      }
      __syncthreads();
#pragma unroll
      for (int kk = 0; kk < 2; ++kk) {
        bf16x8 a[4], b[4];
        const int koff = (((kk << 2) + l4) << 3) ^ swz;
#pragma unroll
        for (int i = 0; i < 4; ++i) {
          a[i] = *(const bf16x8*)&stage[(wm + (i << 4) + l15) * 64 + koff];
          b[i] = *(const bf16x8*)&stage[8192 + (wn + (i << 4) + l15) * 64 + koff];
        }
#pragma unroll
        for (int i = 0; i < 4; ++i)
#pragma unroll
          for (int j = 0; j < 4; ++j)
            acc[i][j] = __builtin_amdgcn_mfma_f32_16x16x32_bf16(a[i], b[j], acc[i][j], 0, 0, 0);
      }
      __syncthreads();
    }

    if (p == 0) {   // park sr*scale as packed bf16
#pragma unroll
      for (int i = 0; i < 4; ++i)
#pragma unroll
        for (int j = 0; j < 4; ++j) {
          srp[i][j][0] = (unsigned int)f2b(acc[i][j][0] * SCALE_C)
                       | ((unsigned int)f2b(acc[i][j][1] * SCALE_C) << 16);
          srp[i][j][1] = (unsigned int)f2b(acc[i][j][2] * SCALE_C)
                       | ((unsigned int)f2b(acc[i][j][3] * SCALE_C) << 16);
        }
    }
  }

  // phase 2: w in C-frag layout; rowsum shfl-reduce; w -> stage (swizzled)
  const int hb = wn >> 6;
#pragma unroll
  for (int i = 0; i < 4; ++i) {
    const int rl0 = wm + (i << 4) + l4 * 4;
#pragma unroll
    for (int r = 0; r < 4; ++r) {
      const int rl = rl0 + r;
      const unsigned long long mr = mrs[rl * 2 + hb];
      const unsigned long long mf = mfs[rl * 2 + hb];
      float rsum = 0.f;
#pragma unroll
      for (int j = 0; j < 4; ++j) {
        const int cl = wn + (j << 4) + l15;
        const int bit = cl & 63;
        const float srv = b2f((u16)(srp[i][j][r >> 1] >> ((r & 1) * 16)));
        const float sfv = acc[i][j][r] * SCALE_C;
        const float wr = ((mr >> bit) & 1) ? 0.f : __expf(srv);
        const float wf = ((mf >> bit) & 1) ? 0.f : __expf(sfv);
        const float w = wr + GAMMA_C * wf;
        rsum += w;
        const int chunk = cl >> 3, within = cl & 7;
        const int wchunk = (chunk & 8) | ((chunk ^ rl) & 7);
        stage[rl * 128 + wchunk * 8 + within] = f2b(w);
      }
      rsum += __shfl_xor(rsum, 1);
      rsum += __shfl_xor(rsum, 2);
      rsum += __shfl_xor(rsum, 4);
      rsum += __shfl_xor(rsum, 8);
      if (l15 == 0) atomicAdd(&lvec[m0 + rl], rsum);
    }
  }
  __syncthreads();

  // phase 3: coalesced 16B stores
  const int rr = tid >> 1, hh = tid & 1;
  const int grow = m0 + rr;
#pragma unroll
  for (int cb = 0; cb < 8; ++cb) {
    const int chunkidx = hh * 8 + cb;
    const int rchunk = (chunkidx & 8) | ((chunkidx ^ rr) & 7);
    uint4 raw = *(const uint4*)&stage[rr * 128 + rchunk * 8];
    *(uint4*)&W[(size_t)grow * 8192 + n0 + chunkidx * 8] = raw;
  }
}

// ------ fused: h = (sum of 8 bf16 slabs)/lvec + residual; out = LN(h) ------
__global__ __launch_bounds__(256)
void pv_ln(const u16* __restrict__ slabs, const float* __restrict__ lvec,
           const u16* __restrict__ res, const void* __restrict__ g,
           const void* __restrict__ be, u16* __restrict__ out,
           const int* __restrict__ flags) {
  const int row = blockIdx.x, tid = threadIdx.x;
  const int f32m = flags[2];
  const size_t off = (size_t)row * 512 + tid * 2;
  const float linv = 1.0f / lvec[row];
  float o0 = 0.f, o1 = 0.f;
#pragma unroll
  for (int s = 0; s < 8; ++s) {
    o0 += b2f(slabs[off + s * SLAB]);
    o1 += b2f(slabs[off + 1 + s * SLAB]);
  }
  const float v0 = o0 * linv + b2f(res[off]);
  const float v1 = o1 * linv + b2f(res[off + 1]);
  __shared__ float r1[256], r2[256];
  r1[tid] = v0 + v1;
  r2[tid] = v0 * v0 + v1 * v1;
  __syncthreads();
  for (int s = 128; s > 0; s >>= 1) {
    if (tid < s) { r1[tid] += r1[tid + s]; r2[tid] += r2[tid + s]; }
    __syncthreads();
  }
  const float mu = r1[0] * (1.f / 512.f);
  const float var = r2[0] * (1.f / 512.f) - mu * mu;
  const float rs = rsqrtf(var + 1e-5f);
  out[off]     = f2b((v0 - mu) * rs * fl_at(g, tid * 2, f32m)     + fl_at(be, tid * 2, f32m));
  out[off + 1] = f2b((v1 - mu) * rs * fl_at(g, tid * 2 + 1, f32m) + fl_at(be, tid * 2 + 1, f32m));
}

// ---- fused: ff = slab0+slab1 + bias; out = LN(ff + residual) (bf16) -------
__global__ __launch_bounds__(256)
void ff_ln(const u16* __restrict__ slabs, const void* __restrict__ bias,
           const u16* __restrict__ res, const void* __restrict__ g,
           const void* __restrict__ be, u16* __restrict__ out,
           const int* __restrict__ flags) {
  const int row = blockIdx.x, tid = threadIdx.x;
  const int f32m = flags[2];
  const size_t off = (size_t)row * 512 + tid * 2;
  const float v0 = b2f(slabs[off]) + b2f(slabs[off + SLAB])
                 + fl_at(bias, tid * 2, f32m) + b2f(res[off]);
  const float v1 = b2f(slabs[off + 1]) + b2f(slabs[off + 1 + SLAB])
                 + fl_at(bias, tid * 2 + 1, f32m) + b2f(res[off + 1]);
  __shared__ float r1[256], r2[256];
  r1[tid] = v0 + v1;
  r2[tid] = v0 * v0 + v1 * v1;
  __syncthreads();
  for (int s = 128; s > 0; s >>= 1) {
    if (tid < s) { r1[tid] += r1[tid + s]; r2[tid] += r2[tid + s]; }
    __syncthreads();
  }
  const float mu = r1[0] * (1.f / 512.f);
  const float var = r2[0] * (1.f / 512.f) - mu * mu;
  const float rs = rsqrtf(var + 1e-5f);
  out[off]     = f2b((v0 - mu) * rs * fl_at(g, tid * 2, f32m)     + fl_at(be, tid * 2, f32m));
  out[off + 1] = f2b((v1 - mu) * rs * fl_at(g, tid * 2 + 1, f32m) + fl_at(be, tid * 2 + 1, f32m));
}

// ------------------------------- host driver --------------------------------
extern "C" void kernel_launch(void* const* d_in, const int* in_sizes, int n_in,
                              void* d_out, int out_size, void* d_ws, size_t ws_size,
                              hipStream_t stream) {
  (void)in_sizes; (void)n_in; (void)out_size; (void)ws_size;
  const void* x = d_in[0];
  const void* dropidx = d_in[1];
  const void* rmask = d_in[2];
  const void* fmask = d_in[3];

  char* base = (char*)d_ws;
  size_t cur = 0;
  auto alloc = [&](size_t b) -> void* {
    void* p = base + cur;
    cur += (b + 255) & ~(size_t)255;
    return p;
  };

  int* flags = (int*)alloc(256);
  u16* Wt = (u16*)alloc((size_t)11 * 512 * 512 * 2);   // 10 QKV + head, transposed
  u16* wff1t = (u16*)alloc((size_t)2048 * 512 * 2);
  u16* wff2t = (u16*)alloc((size_t)512 * 2048 * 2);
  const size_t ND2 = (size_t)8192 * 512 * 2;
  u16* dropx = (u16*)alloc(ND2);
  u16* P = (u16*)alloc((size_t)8192 * 2048 * 2);       // Qr|Kr|Qf|Kf, ld 2048
  u16* Vt = (u16*)alloc(ND2);                          // V^T [512][8192]
  u16* H1 = (u16*)alloc(ND2);
  u16* H2 = (u16*)alloc(ND2);
  u16* FF1 = (u16*)alloc((size_t)8192 * 2048 * 2);
  unsigned char* bmr = (unsigned char*)alloc((size_t)8192 * 1024);
  unsigned char* bmf = (unsigned char*)alloc((size_t)8192 * 1024);
  float* lvec = (float*)alloc((size_t)8192 * 4);
  u16* slabs = (u16*)alloc((size_t)8 * SLAB * 2);      // 8 bf16 partial slabs
  u16* Wb = (u16*)alloc((size_t)8192 * 8192 * 2);      // score weights w

  detect_all<<<1, 256, 0, stream>>>((const unsigned char*)rmask, x, dropidx, flags);
  bitmask_prep<<<32768, 256, 0, stream>>>(rmask, fmask, bmr, bmf, flags);

  const dim3 tb(32, 8);
  PtrPack wp;
  for (int i = 0; i < 5; ++i) wp.p[i] = d_in[4 + i];       // enc
  for (int i = 0; i < 5; ++i) wp.p[5 + i] = d_in[9 + i];   // dec
  wp.p[10] = d_in[24];                                      // head
  transpose_cvt_b<<<dim3(16, 16, 11), tb, 0, stream>>>(wp, Wt, flags);
  transpose_cvt<<<dim3(64, 16), tb, 0, stream>>>(d_in[14], wff1t, 512, 2048, flags);
  transpose_cvt<<<dim3(16, 64), tb, 0, stream>>>(d_in[16], wff2t, 2048, 512, flags);

  cvt_to_bf16<<<(8192 * 512 + 255) / 256, 256, 0, stream>>>(x, dropx, 8192 * 512, flags);
  zero_drop<<<(NG + 255) / 256, 256, 0, stream>>>(dropx, dropidx, flags);

  auto gemm = [&](const u16* A, int lda, const u16* Bt, int ldb, u16* Cc, int ldc,
                  int M, int Nn, int K, int mode, const void* bias, u16* aux,
                  int zc, long long slabStride) {
    gemm_bt<<<dim3(Nn / 128, M / 128, zc), 256, 0, stream>>>(
        A, lda, Bt, ldb, Cc, ldc, K, mode, bias, flags, aux, slabStride);
  };

  auto attention = [&](const u16* Hin, const u16* Wqkv, const void* lnG,
                       const void* lnB, u16* outLN) {
    zero_f32<<<32, 256, 0, stream>>>(lvec, 8192);
    gemm(Hin, 512, Wqkv, 512, P, 2048, 8192, 2560, 512, 2, nullptr, Vt, 1, 0);
    score_fused<<<dim3(64, 64), 256, 0, stream>>>(P, bmr, bmf, Wb, lvec);
    // PV: 8 split-K chunks of 1024 into bf16 slabs
    gemm(Wb, 8192, Vt, 8192, slabs, 512, 8192, 512, 1024, 0, nullptr, nullptr,
         8, (long long)SLAB);
    pv_ln<<<8192, 256, 0, stream>>>(slabs, lvec, Hin, lnG, lnB, outLN, flags);
  };

  // encoder
  attention(dropx, Wt, d_in[18], d_in[19], H1);
  gemm(H1, 512, wff1t, 512, FF1, 2048, 8192, 2048, 512, 1, d_in[15], nullptr, 1, 0);
  // FF2: split-K 2 x 1024 into slabs; bias+residual+LN fused in ff_ln
  gemm(FF1, 2048, wff2t, 2048, slabs, 512, 8192, 512, 1024, 0, nullptr, nullptr,
       2, (long long)SLAB);
  ff_ln<<<8192, 256, 0, stream>>>(slabs, d_in[17], H1, d_in[20], d_in[21], H2, flags);
  // decoder
  attention(H2, Wt + (size_t)5 * 512 * 512, d_in[22], d_in[23], H1);
  // head: split-K 2 x 256 into slabs; bias + gather fused
  gemm(H1, 512, Wt + (size_t)10 * 512 * 512, 512, slabs, 512, 8192, 512, 256, 0,
       nullptr, nullptr, 2, (long long)SLAB);
  gather_out_k<<<(NG + 255) / 256, 256, 0, stream>>>(x, slabs, d_in[25], dropidx,
                                                     d_out, flags);
}

// Round 7
// 1446.198 us; speedup vs baseline: 1.1078x; 1.1078x over previous
//
#include <hip/hip_runtime.h>
#include <cstdint>
#include <cstddef>

// ---------------------------------------------------------------------------
// SpaceFormerImputation on MI355X (gfx950) — round 7.
// vs round 6 (1602 us): (256,4) on score_fused caused VGPR 84->64 spills
// (WRITE 148->316 MB) -> 234->270 us. Reverted to (256,3).
// PV rewritten as pv_big: 512-thread blocks, 128x256 tile, BK=64, split-K z=8
// (grid 2x64x8): A re-read x2 not x4, 2x MFMA per staged byte. Epilogue
// stores packed 4-row groups (coalesced 8B), summed by pv_ln4 (4 rows/block).
// Runtime dtype flags: [0] mask fmt 0=i32,1=u8,2=bf16,3=f32; [1] idx int64;
// [2] float world f32(1)/bf16(0).
// ---------------------------------------------------------------------------

typedef unsigned short u16;
typedef __bf16 bf16x8 __attribute__((ext_vector_type(8)));
typedef float f32x4 __attribute__((ext_vector_type(4)));

#define GAMMA_C 0.5f
#define SCALE_C 0.04419417382415922f   // 1/sqrt(512)
#define NG      (8192 * 102)
#define SLAB    ((size_t)8192 * 512)

__device__ __forceinline__ float b2f(u16 u) {
  union { unsigned int i; float f; } c; c.i = ((unsigned int)u) << 16; return c.f;
}
__device__ __forceinline__ u16 f2b(float f) {
  union { float f; unsigned int i; } c; c.f = f;
  unsigned int u = c.i + 0x7FFFu + ((c.i >> 16) & 1u);
  return (u16)(u >> 16);
}
__device__ __forceinline__ float gelu_exact(float x) {
  return 0.5f * x * (1.0f + erff(x * 0.70710678118654752f));
}
__device__ __forceinline__ int idx_at(const void* p, int i, int i64) {
  return i64 ? (int)((const long long*)p)[i] : ((const int*)p)[i];
}
__device__ __forceinline__ float fl_at(const void* p, size_t i, int f32m) {
  return f32m ? ((const float*)p)[i] : b2f(((const u16*)p)[i]);
}
__device__ __forceinline__ void mask8(const void* m, size_t base, int f, bool o[8]) {
  if (f == 1) {
    unsigned long long v = *(const unsigned long long*)((const unsigned char*)m + base);
#pragma unroll
    for (int e = 0; e < 8; ++e) o[e] = ((v >> (8 * e)) & 0xFF) != 0;
  } else if (f == 0) {
    const uint4 a = *(const uint4*)((const int*)m + base);
    const uint4 b = *(const uint4*)((const int*)m + base + 4);
    o[0] = a.x; o[1] = a.y; o[2] = a.z; o[3] = a.w;
    o[4] = b.x; o[5] = b.y; o[6] = b.z; o[7] = b.w;
  } else if (f == 2) {
    const uint4 v = *(const uint4*)((const u16*)m + base);
    const u16* p = (const u16*)&v;
#pragma unroll
    for (int e = 0; e < 8; ++e) o[e] = p[e] != 0;
  } else {
    const uint4 a = *(const uint4*)((const float*)m + base);
    const uint4 b = *(const uint4*)((const float*)m + base + 4);
    o[0] = a.x; o[1] = a.y; o[2] = a.z; o[3] = a.w;
    o[4] = b.x; o[5] = b.y; o[6] = b.z; o[7] = b.w;
  }
}

#define GLD16(g, l) __builtin_amdgcn_global_load_lds(                         \
    (const __attribute__((address_space(1))) void*)(g),                       \
    (__attribute__((address_space(3))) void*)(l), 16, 0, 0)

// ----------------------------- dtype sniffing ------------------------------
__global__ void detect_all(const unsigned char* __restrict__ rmask,
                           const void* __restrict__ xin,
                           const void* __restrict__ idx,
                           int* __restrict__ flags) {
  __shared__ int nz[4];
  __shared__ int mx, bl;
  const int t = threadIdx.x;
  if (t < 4) nz[t] = 0;
  if (t == 0) { mx = 0; bl = 0; }
  __syncthreads();
  int cnt = 0, lm = 0;
  for (int i = t; i < 4096; i += 256) {
    const int v = rmask[i];
    if (v) { ++cnt; if (v > lm) lm = v; }
  }
  if (cnt) atomicAdd(&nz[t & 3], cnt);
  if (lm) atomicMax(&mx, lm);
  int bcnt = 0;
  for (int i = t; i < 2048; i += 256) {
    const u16 u = ((const u16*)xin)[2 * i];
    const int e = (u >> 7) & 0xFF;
    if ((e >= 110 && e <= 141) || u == 0) ++bcnt;
  }
  atomicAdd(&bl, bcnt);
  __syncthreads();
  if (t == 0) {
    int f;
    if (nz[1] == 0 && nz[2] == 0 && nz[3] == 0) f = 0;
    else if (nz[0] == 0 && nz[1] == 0) f = 3;
    else if (mx <= 1) f = 1;
    else f = 2;
    flags[0] = f;
    flags[2] = (bl >= 1536) ? 0 : 1;
    int ok = 1, prev = -1;
    for (int j = 0; j < 102; ++j) {
      const int v = ((const int*)idx)[j];
      if (v <= prev || v < 0 || v >= 512) { ok = 0; break; }
      prev = v;
    }
    flags[1] = ok ? 0 : 1;
  }
}

// ----------------------- bitmask pack (1 bit/element) ----------------------
__global__ void bitmask_prep(const void* __restrict__ mr, const void* __restrict__ mf,
                             unsigned char* __restrict__ bmr, unsigned char* __restrict__ bmf,
                             const int* __restrict__ flags) {
  const int i = blockIdx.x * 256 + threadIdx.x;   // byte index, 8192*1024 total
  const int f = flags[0];
  bool mk[8];
  mask8(mr, (size_t)i * 8, f, mk);
  unsigned char b = 0;
#pragma unroll
  for (int e = 0; e < 8; ++e) b |= (unsigned char)mk[e] << e;
  bmr[i] = b;
  mask8(mf, (size_t)i * 8, f, mk);
  b = 0;
#pragma unroll
  for (int e = 0; e < 8; ++e) b |= (unsigned char)mk[e] << e;
  bmf[i] = b;
}

// ---------------------- transpose + convert to bf16 ------------------------
struct PtrPack { const void* p[11]; };
__global__ void transpose_cvt_b(PtrPack srcs, u16* __restrict__ out,
                                const int* __restrict__ flags) {
  __shared__ u16 tile[32][33];
  const void* in = srcs.p[blockIdx.z];
  u16* o = out + (size_t)blockIdx.z * 512 * 512;
  const int f32m = flags[2];
  const int c0 = blockIdx.x * 32, r0 = blockIdx.y * 32;
  const int tx = threadIdx.x, ty = threadIdx.y;   // (32,8)
  for (int i = ty; i < 32; i += 8) {
    const size_t src = (size_t)(r0 + i) * 512 + (c0 + tx);
    tile[i][tx] = f32m ? f2b(((const float*)in)[src]) : ((const u16*)in)[src];
  }
  __syncthreads();
  for (int i = ty; i < 32; i += 8)
    o[(size_t)(c0 + i) * 512 + (r0 + tx)] = tile[tx][i];
}
__global__ void transpose_cvt(const void* __restrict__ in, u16* __restrict__ out,
                              int R, int C, const int* __restrict__ flags) {
  __shared__ u16 tile[32][33];
  const int f32m = flags[2];
  const int c0 = blockIdx.x * 32, r0 = blockIdx.y * 32;
  const int tx = threadIdx.x, ty = threadIdx.y;
  for (int i = ty; i < 32; i += 8) {
    const size_t src = (size_t)(r0 + i) * C + (c0 + tx);
    tile[i][tx] = f32m ? f2b(((const float*)in)[src]) : ((const u16*)in)[src];
  }
  __syncthreads();
  for (int i = ty; i < 32; i += 8)
    out[(size_t)(c0 + i) * R + (r0 + tx)] = tile[tx][i];
}

// ------------------------------ small utils --------------------------------
__global__ void cvt_to_bf16(const void* __restrict__ in, u16* __restrict__ out,
                            int n, const int* __restrict__ flags) {
  const int i = blockIdx.x * blockDim.x + threadIdx.x;
  if (i < n)
    out[i] = flags[2] ? f2b(((const float*)in)[i]) : ((const u16*)in)[i];
}
__global__ void zero_f32(float* __restrict__ p, int n) {
  const int i = blockIdx.x * blockDim.x + threadIdx.x;
  if (i < n) p[i] = 0.f;
}
__global__ void zero_drop(u16* __restrict__ dx, const void* __restrict__ idx,
                          const int* __restrict__ flags) {
  const int i = blockIdx.x * blockDim.x + threadIdx.x;
  if (i < NG) {
    const int row = i / 102;
    dx[(size_t)row * 512 + idx_at(idx, i, flags[1])] = 0;
  }
}
// out0 = x gathered; out1 = (headslab0+headslab1+head_b) gathered (row-major slabs)
__global__ void gather_out_k(const void* __restrict__ x, const u16* __restrict__ hs,
                             const void* __restrict__ hb,
                             const void* __restrict__ idx, void* __restrict__ out,
                             const int* __restrict__ flags) {
  const int i = blockIdx.x * blockDim.x + threadIdx.x;
  if (i < NG) {
    const int row = i / 102;
    const int c = idx_at(idx, i, flags[1]);
    const size_t src = (size_t)row * 512 + c;
    const float hv = b2f(hs[src]) + b2f(hs[src + SLAB]) + fl_at(hb, c, flags[2]);
    if (flags[2]) {
      ((float*)out)[i] = ((const float*)x)[src];
      ((float*)out)[NG + i] = hv;
    } else {
      ((u16*)out)[i] = ((const u16*)x)[src];
      ((u16*)out)[NG + i] = f2b(hv);
    }
  }
}

// ------------------------------ GEMM (B^T) ---------------------------------
// C[M,Nn] = A[M,K] @ Bt[Nn,K]^T (bf16). 128x128 tile, BK=64, 2x2 waves,
// 16x16x32 MFMA, XOR-swizzled LDS. grid.z = split-K chunk (kShift=z*K,
// C += z*slabStride). modes: 0 plain(+bias), 1 gelu(+bias), 2 QKV split.
__global__ __launch_bounds__(256)
void gemm_bt(const u16* __restrict__ A, int lda,
             const u16* __restrict__ Bt, int ldb,
             u16* __restrict__ C, int ldc,
             int K, int mode, const void* __restrict__ bias,
             const int* __restrict__ flags, u16* __restrict__ aux,
             long long slabStride) {
  __shared__ alignas(16) u16 smem[16384];
  u16* As = smem;
  u16* Bs = smem + 8192;
  const int tid = threadIdx.x;
  const int lane = tid & 63, wave = tid >> 6;
  const int l15 = lane & 15, l4 = lane >> 4;
  const int wm = (wave >> 1) << 6, wn = (wave & 1) << 6;
  const int m0 = blockIdx.y << 7, n0 = blockIdx.x << 7;
  const size_t kShift = (size_t)blockIdx.z * (size_t)K;
  C += (size_t)blockIdx.z * (size_t)slabStride;

  f32x4 acc[4][4];
#pragma unroll
  for (int i = 0; i < 4; ++i)
#pragma unroll
    for (int j = 0; j < 4; ++j) acc[i][j] = (f32x4){0.f, 0.f, 0.f, 0.f};

  const int lrow = lane >> 3;
  const int lcg = (lane & 7) ^ lrow;
  const u16* aG = A + kShift + (size_t)(m0 + wave * 8 + lrow) * lda + lcg * 8;
  const u16* bG = Bt + kShift + (size_t)(n0 + wave * 8 + lrow) * ldb + lcg * 8;
  u16* asDst = &As[(wave * 8) * 64];
  u16* bsDst = &Bs[(wave * 8) * 64];
  const int swz = (l15 & 7) << 3;

  for (int k0 = 0; k0 < K; k0 += 64) {
#pragma unroll
    for (int r = 0; r < 4; ++r) {
      GLD16(aG + (size_t)(r * 32) * lda + k0, asDst + r * 32 * 64);
      GLD16(bG + (size_t)(r * 32) * ldb + k0, bsDst + r * 32 * 64);
    }
    __syncthreads();
#pragma unroll
    for (int kk = 0; kk < 2; ++kk) {
      bf16x8 a[4], b[4];
      const int koff = (((kk << 2) + l4) << 3) ^ swz;
#pragma unroll
      for (int i = 0; i < 4; ++i) {
        a[i] = *(const bf16x8*)&As[(wm + (i << 4) + l15) * 64 + koff];
        b[i] = *(const bf16x8*)&Bs[(wn + (i << 4) + l15) * 64 + koff];
      }
#pragma unroll
      for (int i = 0; i < 4; ++i)
#pragma unroll
        for (int j = 0; j < 4; ++j)
          acc[i][j] = __builtin_amdgcn_mfma_f32_16x16x32_bf16(a[i], b[j], acc[i][j], 0, 0, 0);
    }
    __syncthreads();
  }

  const int f32m = flags[2];

  if (mode == 2 && n0 >= 2048) {        // V part -> transposed store into Vt
#pragma unroll
    for (int i = 0; i < 4; ++i) {
      const int rbase = m0 + wm + (i << 4) + l4 * 4;
#pragma unroll
      for (int j = 0; j < 4; ++j) {
        const int gn = n0 - 2048 + wn + (j << 4) + l15;
        ushort4 pk;
        pk.x = f2b(acc[i][j][0]); pk.y = f2b(acc[i][j][1]);
        pk.z = f2b(acc[i][j][2]); pk.w = f2b(acc[i][j][3]);
        *(ushort4*)&aux[(size_t)gn * 8192 + rbase] = pk;
      }
    }
    return;
  }

  // phase 1: transform in C-frag layout, bf16 into swizzled LDS
#pragma unroll
  for (int i = 0; i < 4; ++i) {
    const int rl0 = wm + (i << 4) + l4 * 4;
#pragma unroll
    for (int j = 0; j < 4; ++j) {
      const int cl = wn + (j << 4) + l15;
      float bv = 0.f;
      if (bias) bv = fl_at(bias, n0 + cl, f32m);
      const int chunk = cl >> 3, within = cl & 7;
#pragma unroll
      for (int r = 0; r < 4; ++r) {
        const int rl = rl0 + r;
        float v = acc[i][j][r] + bv;
        if (mode == 1) v = gelu_exact(v);
        const int wchunk = (chunk & 8) | ((chunk ^ rl) & 7);
        smem[rl * 128 + wchunk * 8 + within] = f2b(v);
      }
    }
  }
  __syncthreads();

  // phase 2: vectorized stores
  const int r = tid >> 1, h = tid & 1;
  const int grow = m0 + r;
#pragma unroll
  for (int cb = 0; cb < 8; ++cb) {
    const int chunkidx = h * 8 + cb;
    const int rchunk = (chunkidx & 8) | ((chunkidx ^ r) & 7);
    uint4 raw = *(const uint4*)&smem[r * 128 + rchunk * 8];
    *(uint4*)&C[(size_t)grow * ldc + n0 + chunkidx * 8] = raw;
  }
}

// --------------------------- fused dual score v2 ---------------------------
// (256,3): 84 VGPR, no spills — (256,4) spilled (r6: VGPR 64, WRITE 2x).
__global__ __launch_bounds__(256, 3)
void score_fused(const u16* __restrict__ P,          // [8192][2048] Qr|Kr|Qf|Kf
                 const unsigned char* __restrict__ bmr,
                 const unsigned char* __restrict__ bmf,
                 u16* __restrict__ W, float* __restrict__ lvec) {
  __shared__ alignas(16) u16 stage[16384];            // 32 KB staging / w-tile
  __shared__ unsigned long long mrs[256], mfs[256];   // 4 KB mask bit-tiles
  const int tid = threadIdx.x;
  const int lane = tid & 63, wave = tid >> 6;
  const int l15 = lane & 15, l4 = lane >> 4;
  const int wm = (wave >> 1) << 6, wn = (wave & 1) << 6;
  const int m0 = blockIdx.y << 7, n0 = blockIdx.x << 7;

  {  // mask tiles -> LDS (ordering vs phase 2 covered by K-loop barriers)
    const int r = tid >> 1, hh = tid & 1;
    const size_t mo = (size_t)(m0 + r) * 1024 + (n0 >> 3) + hh * 8;
    mrs[tid] = *(const unsigned long long*)&bmr[mo];
    mfs[tid] = *(const unsigned long long*)&bmf[mo];
  }

  const int lrow = lane >> 3;
  const int lcg = (lane & 7) ^ lrow;
  const int swz = (l15 & 7) << 3;
  u16* asDst = &stage[(wave * 8) * 64];
  u16* bsDst = &stage[8192 + (wave * 8) * 64];

  unsigned int srp[4][4][2];   // packed bf16 sr*scale
  f32x4 acc[4][4];

  for (int p = 0; p < 2; ++p) {
#pragma unroll
    for (int i = 0; i < 4; ++i)
#pragma unroll
      for (int j = 0; j < 4; ++j) acc[i][j] = (f32x4){0.f, 0.f, 0.f, 0.f};

    const u16* aG = P + (p ? 1024 : 0) + (size_t)(m0 + wave * 8 + lrow) * 2048 + lcg * 8;
    const u16* bG = P + (p ? 1536 : 512) + (size_t)(n0 + wave * 8 + lrow) * 2048 + lcg * 8;

    for (int k0 = 0; k0 < 512; k0 += 64) {
#pragma unroll
      for (int r = 0; r < 4; ++r) {
        GLD16(aG + (size_t)(r * 32) * 2048 + k0, asDst + r * 32 * 64);
        GLD16(bG + (size_t)(r * 32) * 2048 + k0, bsDst + r * 32 * 64);
      }
      __syncthreads();
#pragma unroll
      for (int kk = 0; kk < 2; ++kk) {
        bf16x8 a[4], b[4];
        const int koff = (((kk << 2) + l4) << 3) ^ swz;
#pragma unroll
        for (int i = 0; i < 4; ++i) {
          a[i] = *(const bf16x8*)&stage[(wm + (i << 4) + l15) * 64 + koff];
          b[i] = *(const bf16x8*)&stage[8192 + (wn + (i << 4) + l15) * 64 + koff];
        }
#pragma unroll
        for (int i = 0; i < 4; ++i)
#pragma unroll
          for (int j = 0; j < 4; ++j)
            acc[i][j] = __builtin_amdgcn_mfma_f32_16x16x32_bf16(a[i], b[j], acc[i][j], 0, 0, 0);
      }
      __syncthreads();
    }

    if (p == 0) {   // park sr*scale as packed bf16
#pragma unroll
      for (int i = 0; i < 4; ++i)
#pragma unroll
        for (int j = 0; j < 4; ++j) {
          srp[i][j][0] = (unsigned int)f2b(acc[i][j][0] * SCALE_C)
                       | ((unsigned int)f2b(acc[i][j][1] * SCALE_C) << 16);
          srp[i][j][1] = (unsigned int)f2b(acc[i][j][2] * SCALE_C)
                       | ((unsigned int)f2b(acc[i][j][3] * SCALE_C) << 16);
        }
    }
  }

  // phase 2: w in C-frag layout; rowsum shfl-reduce; w -> stage (swizzled)
  const int hb = wn >> 6;
#pragma unroll
  for (int i = 0; i < 4; ++i) {
    const int rl0 = wm + (i << 4) + l4 * 4;
#pragma unroll
    for (int r = 0; r < 4; ++r) {
      const int rl = rl0 + r;
      const unsigned long long mr = mrs[rl * 2 + hb];
      const unsigned long long mf = mfs[rl * 2 + hb];
      float rsum = 0.f;
#pragma unroll
      for (int j = 0; j < 4; ++j) {
        const int cl = wn + (j << 4) + l15;
        const int bit = cl & 63;
        const float srv = b2f((u16)(srp[i][j][r >> 1] >> ((r & 1) * 16)));
        const float sfv = acc[i][j][r] * SCALE_C;
        const float wr = ((mr >> bit) & 1) ? 0.f : __expf(srv);
        const float wf = ((mf >> bit) & 1) ? 0.f : __expf(sfv);
        const float w = wr + GAMMA_C * wf;
        rsum += w;
        const int chunk = cl >> 3, within = cl & 7;
        const int wchunk = (chunk & 8) | ((chunk ^ rl) & 7);
        stage[rl * 128 + wchunk * 8 + within] = f2b(w);
      }
      rsum += __shfl_xor(rsum, 1);
      rsum += __shfl_xor(rsum, 2);
      rsum += __shfl_xor(rsum, 4);
      rsum += __shfl_xor(rsum, 8);
      if (l15 == 0) atomicAdd(&lvec[m0 + rl], rsum);
    }
  }
  __syncthreads();

  // phase 3: coalesced 16B stores
  const int rr = tid >> 1, hh = tid & 1;
  const int grow = m0 + rr;
#pragma unroll
  for (int cb = 0; cb < 8; ++cb) {
    const int chunkidx = hh * 8 + cb;
    const int rchunk = (chunkidx & 8) | ((chunkidx ^ rr) & 7);
    uint4 raw = *(const uint4*)&stage[rr * 128 + rchunk * 8];
    *(uint4*)&W[(size_t)grow * 8192 + n0 + chunkidx * 8] = raw;
  }
}

// ------------------------------ PV big-tile --------------------------------
// Oslab[z] = W[128-row stripe] @ V over K-chunk z. 512 threads (8 waves, 2x4),
// tile 128x256, BK=64, grid (2,64,8). Slab store: packed 4-row groups
// [rowgroup][col][4] -> coalesced ushort4 stores straight from C-frag regs.
__global__ __launch_bounds__(512)
void pv_big(const u16* __restrict__ W, const u16* __restrict__ Vt,
            u16* __restrict__ slabs) {
  __shared__ alignas(16) u16 smem[24576];   // As 128x64 (16KB) + Bs 256x64 (32KB)
  u16* As = smem;
  u16* Bs = smem + 8192;
  const int tid = threadIdx.x;
  const int lane = tid & 63, wave = tid >> 6;      // 8 waves
  const int l15 = lane & 15, l4 = lane >> 4;
  const int wm = (wave >> 2) << 6;                 // 2 M-groups
  const int wn = (wave & 3) << 6;                  // 4 N-groups
  const int m0 = blockIdx.y << 7, n0 = blockIdx.x << 8;
  const int kbase = blockIdx.z << 10;              // 8 chunks x 1024
  u16* slab = slabs + (size_t)blockIdx.z * SLAB;

  f32x4 acc[4][4];
#pragma unroll
  for (int i = 0; i < 4; ++i)
#pragma unroll
    for (int j = 0; j < 4; ++j) acc[i][j] = (f32x4){0.f, 0.f, 0.f, 0.f};

  const int lrow = lane >> 3;
  const int lcg = (lane & 7) ^ lrow;
  const u16* aG = W + (size_t)(m0 + wave * 8 + lrow) * 8192 + kbase + lcg * 8;
  const u16* bG = Vt + (size_t)(n0 + wave * 8 + lrow) * 8192 + kbase + lcg * 8;
  u16* asDst = &As[(wave * 8) * 64];
  u16* bsDst = &Bs[(wave * 8) * 64];
  const int swz = (l15 & 7) << 3;

  for (int k0 = 0; k0 < 1024; k0 += 64) {
#pragma unroll
    for (int r = 0; r < 2; ++r)          // A: 128 rows = 2 x (8 waves x 8 rows)
      GLD16(aG + (size_t)(r * 64) * 8192 + k0, asDst + r * 64 * 64);
#pragma unroll
    for (int r = 0; r < 4; ++r)          // B: 256 rows = 4 x 64
      GLD16(bG + (size_t)(r * 64) * 8192 + k0, bsDst + r * 64 * 64);
    __syncthreads();
#pragma unroll
    for (int kk = 0; kk < 2; ++kk) {
      bf16x8 a[4], b[4];
      const int koff = (((kk << 2) + l4) << 3) ^ swz;
#pragma unroll
      for (int i = 0; i < 4; ++i) {
        a[i] = *(const bf16x8*)&As[(wm + (i << 4) + l15) * 64 + koff];
        b[i] = *(const bf16x8*)&Bs[(wn + (i << 4) + l15) * 64 + koff];
      }
#pragma unroll
      for (int i = 0; i < 4; ++i)
#pragma unroll
        for (int j = 0; j < 4; ++j)
          acc[i][j] = __builtin_amdgcn_mfma_f32_16x16x32_bf16(a[i], b[j], acc[i][j], 0, 0, 0);
    }
    __syncthreads();
  }

  // packed store: rows rbase..rbase+3 (one group), col gn -> 8B per (i,j)
#pragma unroll
  for (int i = 0; i < 4; ++i) {
    const int rbase = m0 + wm + (i << 4) + l4 * 4;
#pragma unroll
    for (int j = 0; j < 4; ++j) {
      const int gn = n0 + wn + (j << 4) + l15;
      ushort4 pk;
      pk.x = f2b(acc[i][j][0]); pk.y = f2b(acc[i][j][1]);
      pk.z = f2b(acc[i][j][2]); pk.w = f2b(acc[i][j][3]);
      *(ushort4*)&slab[((size_t)(rbase >> 2) * 512 + gn) * 4] = pk;
    }
  }
}

// -- pv_ln4: sum 8 packed slabs, /lvec, +residual, LN. 4 rows per block. ----
__global__ __launch_bounds__(512)
void pv_ln4(const u16* __restrict__ slabs, const float* __restrict__ lvec,
            const u16* __restrict__ res, const void* __restrict__ g,
            const void* __restrict__ be, u16* __restrict__ out,
            const int* __restrict__ flags) {
  const int gid = blockIdx.x;            // row group (4 rows)
  const int col = threadIdx.x;           // 512 cols
  const int lane = col & 63, wave = col >> 6;
  const int f32m = flags[2];
  float o[4] = {0.f, 0.f, 0.f, 0.f};
  const size_t base = ((size_t)gid * 512 + col) * 4;
#pragma unroll
  for (int s = 0; s < 8; ++s) {
    const ushort4 v = *(const ushort4*)&slabs[s * SLAB + base];
    o[0] += b2f(v.x); o[1] += b2f(v.y); o[2] += b2f(v.z); o[3] += b2f(v.w);
  }
  float v[4];
#pragma unroll
  for (int q = 0; q < 4; ++q) {
    const int grow = gid * 4 + q;
    v[q] = o[q] / lvec[grow] + b2f(res[(size_t)grow * 512 + col]);
  }
  __shared__ float s1[4][8], s2[4][8];
#pragma unroll
  for (int q = 0; q < 4; ++q) {
    float sm = v[q], sq = v[q] * v[q];
#pragma unroll
    for (int d = 1; d < 64; d <<= 1) {
      sm += __shfl_xor(sm, d);
      sq += __shfl_xor(sq, d);
    }
    if (lane == 0) { s1[q][wave] = sm; s2[q][wave] = sq; }
  }
  __syncthreads();
  const float gv = fl_at(g, col, f32m), bv = fl_at(be, col, f32m);
#pragma unroll
  for (int q = 0; q < 4; ++q) {
    float sm = 0.f, sq = 0.f;
#pragma unroll
    for (int w = 0; w < 8; ++w) { sm += s1[q][w]; sq += s2[q][w]; }
    const float mu = sm * (1.f / 512.f);
    const float var = sq * (1.f / 512.f) - mu * mu;
    const float rs = rsqrtf(var + 1e-5f);
    out[(size_t)(gid * 4 + q) * 512 + col] = f2b((v[q] - mu) * rs * gv + bv);
  }
}

// ---- fused: ff = slab0+slab1 + bias; out = LN(ff + residual) (row-major) --
__global__ __launch_bounds__(256)
void ff_ln(const u16* __restrict__ slabs, const void* __restrict__ bias,
           const u16* __restrict__ res, const void* __restrict__ g,
           const void* __restrict__ be, u16* __restrict__ out,
           const int* __restrict__ flags) {
  const int row = blockIdx.x, tid = threadIdx.x;
  const int f32m = flags[2];
  const size_t off = (size_t)row * 512 + tid * 2;
  const float v0 = b2f(slabs[off]) + b2f(slabs[off + SLAB])
                 + fl_at(bias, tid * 2, f32m) + b2f(res[off]);
  const float v1 = b2f(slabs[off + 1]) + b2f(slabs[off + 1 + SLAB])
                 + fl_at(bias, tid * 2 + 1, f32m) + b2f(res[off + 1]);
  __shared__ float r1[256], r2[256];
  r1[tid] = v0 + v1;
  r2[tid] = v0 * v0 + v1 * v1;
  __syncthreads();
  for (int s = 128; s > 0; s >>= 1) {
    if (tid < s) { r1[tid] += r1[tid + s]; r2[tid] += r2[tid + s]; }
    __syncthreads();
  }
  const float mu = r1[0] * (1.f / 512.f);
  const float var = r2[0] * (1.f / 512.f) - mu * mu;
  const float rs = rsqrtf(var + 1e-5f);
  out[off]     = f2b((v0 - mu) * rs * fl_at(g, tid * 2, f32m)     + fl_at(be, tid * 2, f32m));
  out[off + 1] = f2b((v1 - mu) * rs * fl_at(g, tid * 2 + 1, f32m) + fl_at(be, tid * 2 + 1, f32m));
}

// ------------------------------- host driver --------------------------------
extern "C" void kernel_launch(void* const* d_in, const int* in_sizes, int n_in,
                              void* d_out, int out_size, void* d_ws, size_t ws_size,
                              hipStream_t stream) {
  (void)in_sizes; (void)n_in; (void)out_size; (void)ws_size;
  const void* x = d_in[0];
  const void* dropidx = d_in[1];
  const void* rmask = d_in[2];
  const void* fmask = d_in[3];

  char* base = (char*)d_ws;
  size_t cur = 0;
  auto alloc = [&](size_t b) -> void* {
    void* p = base + cur;
    cur += (b + 255) & ~(size_t)255;
    return p;
  };

  int* flags = (int*)alloc(256);
  u16* Wt = (u16*)alloc((size_t)11 * 512 * 512 * 2);   // 10 QKV + head, transposed
  u16* wff1t = (u16*)alloc((size_t)2048 * 512 * 2);
  u16* wff2t = (u16*)alloc((size_t)512 * 2048 * 2);
  const size_t ND2 = (size_t)8192 * 512 * 2;
  u16* dropx = (u16*)alloc(ND2);
  u16* P = (u16*)alloc((size_t)8192 * 2048 * 2);       // Qr|Kr|Qf|Kf, ld 2048
  u16* Vt = (u16*)alloc(ND2);                          // V^T [512][8192]
  u16* H1 = (u16*)alloc(ND2);
  u16* H2 = (u16*)alloc(ND2);
  u16* FF1 = (u16*)alloc((size_t)8192 * 2048 * 2);
  unsigned char* bmr = (unsigned char*)alloc((size_t)8192 * 1024);
  unsigned char* bmf = (unsigned char*)alloc((size_t)8192 * 1024);
  float* lvec = (float*)alloc((size_t)8192 * 4);
  u16* slabs = (u16*)alloc((size_t)8 * SLAB * 2);      // 8 bf16 partial slabs
  u16* Wb = (u16*)alloc((size_t)8192 * 8192 * 2);      // score weights w

  detect_all<<<1, 256, 0, stream>>>((const unsigned char*)rmask, x, dropidx, flags);
  bitmask_prep<<<32768, 256, 0, stream>>>(rmask, fmask, bmr, bmf, flags);

  const dim3 tb(32, 8);
  PtrPack wp;
  for (int i = 0; i < 5; ++i) wp.p[i] = d_in[4 + i];       // enc
  for (int i = 0; i < 5; ++i) wp.p[5 + i] = d_in[9 + i];   // dec
  wp.p[10] = d_in[24];                                      // head
  transpose_cvt_b<<<dim3(16, 16, 11), tb, 0, stream>>>(wp, Wt, flags);
  transpose_cvt<<<dim3(64, 16), tb, 0, stream>>>(d_in[14], wff1t, 512, 2048, flags);
  transpose_cvt<<<dim3(16, 64), tb, 0, stream>>>(d_in[16], wff2t, 2048, 512, flags);

  cvt_to_bf16<<<(8192 * 512 + 255) / 256, 256, 0, stream>>>(x, dropx, 8192 * 512, flags);
  zero_drop<<<(NG + 255) / 256, 256, 0, stream>>>(dropx, dropidx, flags);

  auto gemm = [&](const u16* A, int lda, const u16* Bt, int ldb, u16* Cc, int ldc,
                  int M, int Nn, int K, int mode, const void* bias, u16* aux,
                  int zc, long long slabStride) {
    gemm_bt<<<dim3(Nn / 128, M / 128, zc), 256, 0, stream>>>(
        A, lda, Bt, ldb, Cc, ldc, K, mode, bias, flags, aux, slabStride);
  };

  auto attention = [&](const u16* Hin, const u16* Wqkv, const void* lnG,
                       const void* lnB, u16* outLN) {
    zero_f32<<<32, 256, 0, stream>>>(lvec, 8192);
    gemm(Hin, 512, Wqkv, 512, P, 2048, 8192, 2560, 512, 2, nullptr, Vt, 1, 0);
    score_fused<<<dim3(64, 64), 256, 0, stream>>>(P, bmr, bmf, Wb, lvec);
    pv_big<<<dim3(2, 64, 8), 512, 0, stream>>>(Wb, Vt, slabs);
    pv_ln4<<<2048, 512, 0, stream>>>(slabs, lvec, Hin, lnG, lnB, outLN, flags);
  };

  // encoder
  attention(dropx, Wt, d_in[18], d_in[19], H1);
  gemm(H1, 512, wff1t, 512, FF1, 2048, 8192, 2048, 512, 1, d_in[15], nullptr, 1, 0);
  gemm(FF1, 2048, wff2t, 2048, slabs, 512, 8192, 512, 1024, 0, nullptr, nullptr,
       2, (long long)SLAB);
  ff_ln<<<8192, 256, 0, stream>>>(slabs, d_in[17], H1, d_in[20], d_in[21], H2, flags);
  // decoder
  attention(H2, Wt + (size_t)5 * 512 * 512, d_in[22], d_in[23], H1);
  gemm(H1, 512, Wt + (size_t)10 * 512 * 512, 512, slabs, 512, 8192, 512, 256, 0,
       nullptr, nullptr, 2, (long long)SLAB);
  gather_out_k<<<(NG + 255) / 256, 256, 0, stream>>>(x, slabs, d_in[25], dropidx,
                                                     d_out, flags);
}